// Round 13
// baseline (787.629 us; speedup 1.0000x reference)
//
#include <hip/hip_runtime.h>
#include <hip/hip_bf16.h>
#include <stdint.h>

#define B_  4
#define T_  8192
#define H_  1024
#define NH_ 16
#define D_  64
#define BT_ (B_*T_)

typedef __attribute__((ext_vector_type(8))) __bf16 bf16x8;
typedef __attribute__((ext_vector_type(4))) __bf16 bf16x4;
typedef __attribute__((ext_vector_type(4))) float  f32x4;

__device__ __forceinline__ float phi_f(float x) {
    return x > 0.0f ? x + 1.0f : __expf(x);
}

__device__ __forceinline__ void async_copy16(const void* g, void* l) {
    __builtin_amdgcn_global_load_lds(
        (const __attribute__((address_space(1))) uint32_t*)g,
        (__attribute__((address_space(3))) uint32_t*)l, 16, 0, 0);
}

__global__ void wconv4(const float* __restrict__ s0, const float* __restrict__ s1,
                       const float* __restrict__ s2, const float* __restrict__ s3,
                       __bf16* __restrict__ d0, __bf16* __restrict__ d1,
                       __bf16* __restrict__ d2, __bf16* __restrict__ d3) {
    const float* s; __bf16* d;
    switch (blockIdx.y) {
        case 0: s = s0; d = d0; break;
        case 1: s = s1; d = d1; break;
        case 2: s = s2; d = d2; break;
        default: s = s3; d = d3; break;
    }
    int i = (blockIdx.x * 256 + threadIdx.x) * 4;
    float4 v = *(const float4*)(s + i);
    bf16x4 o;
    o[0] = (__bf16)v.x; o[1] = (__bf16)v.y; o[2] = (__bf16)v.z; o[3] = (__bf16)v.w;
    *(bf16x4*)(d + i) = o;
}

// ---------------------------------------------------------------------------
// FUSED-CONV projection GEMM: Out = epi( A_f32 @ W^T ), bf16 out.
// A: register-staged fp32 (8 x float4 / thread) with PREFETCH DISTANCE 1;
//    cvt -> ds_write into XOR-swizzled bf16 LDS (frag reads identical to the
//    proven round-8 layout).  B: global_load_lds prefetched 1 K-step ahead.
// LDS double-buffered (A 2x16KB + B 2x16KB = 64KB -> 2 blocks/CU).
// Sync per K-step (counted vmcnt — loads stay in flight across the barrier):
//   step1: cvt rA(kt) + ds_write -> Al[p]        (compiler waits A(kt) regs)
//   step2: reload rA <- A(kt+1); DMA B(kt+1) -> Bl[1-p]
//   step3: s_waitcnt vmcnt(12) lgkmcnt(0); s_barrier
//          (retires exactly B(kt)'s 4 DMAs + ds_writes; A(kt+1)8+B(kt+1)4 fly)
//   step4: 32 MFMA from Al[p], Bl[p]
//   step5: s_barrier   (protects buf reuse at kt+1)
// Tail kt=15: step2 skipped, wait vmcnt(0).
// EPI: 0 = Q' = z*phi -> bf16 (aux = Ksum), 1 = phi*mask (K), 2 = mask (V)
// ---------------------------------------------------------------------------
template<int EPI>
__global__ __launch_bounds__(256, 2)
void gemm_fused(const float* __restrict__ A, const __bf16* __restrict__ Wb,
                const float* __restrict__ mask, const float* __restrict__ aux,
                __bf16* __restrict__ Out)
{
    const int orig = blockIdx.x;
    const int wgid = (orig & 7) * 256 + (orig >> 3);   // nwg=2048, bijective
    const int bm = (wgid >> 3) * 128;
    const int bn = (wgid & 7) * 128;
    const int tid  = threadIdx.x;
    const int lane = tid & 63;
    const int wid  = tid >> 6;
    const int wm = wid >> 1, wn = wid & 1;

    __shared__ __align__(16) char Al[2][16384];   // bf16 [128][64], swizzled
    __shared__ __align__(16) char Bl[2][16384];

    f32x4 acc[4][4];
    #pragma unroll
    for (int i = 0; i < 4; ++i)
        #pragma unroll
        for (int j = 0; j < 4; ++j) acc[i][j] = (f32x4)0.0f;

    // A staging: thread covers row ar (0..127), 32-col half ah
    const int ar = tid >> 1;
    const int ah = (tid & 1) * 32;
    const float* aptr = A + (size_t)(bm + ar) * H_ + ah;
    const int awsw = (ar & 7) << 4;

    // B staging
    const int sn = wid * 8 + (lane >> 3);
    const int sc = (lane & 7) * 16;

    float4 rA[8];
    // prologue: A(0) reg loads, B(0) DMA -> Bl[0]
    #pragma unroll
    for (int i = 0; i < 8; ++i) rA[i] = ((const float4*)aptr)[i];
    #pragma unroll
    for (int issue = 0; issue < 4; ++issue) {
        int n = issue * 32 + sn;
        int csw = sc ^ ((n & 7) << 4);
        async_copy16((const char*)(Wb + (size_t)(bn + n) * H_) + csw,
                     (char*)Bl[0] + issue * 4096 + wid * 1024);
    }

    for (int kt = 0; kt < 16; ++kt) {
        const int p = kt & 1;
        // step1: cvt + swizzled ds_write into Al[p]
        {
            char* aw = (char*)Al[p] + ar * 128;
            #pragma unroll
            for (int j = 0; j < 4; ++j) {
                float4 x = rA[2*j], y = rA[2*j+1];
                bf16x8 t;
                t[0]=(__bf16)x.x; t[1]=(__bf16)x.y; t[2]=(__bf16)x.z; t[3]=(__bf16)x.w;
                t[4]=(__bf16)y.x; t[5]=(__bf16)y.y; t[6]=(__bf16)y.z; t[7]=(__bf16)y.w;
                *(bf16x8*)(aw + ((ah * 2 + j * 16) ^ awsw)) = t;
            }
        }
        // step2 + step3
        if (kt < 15) {
            const float* ap = aptr + (kt + 1) * 64;
            #pragma unroll
            for (int i = 0; i < 8; ++i) rA[i] = ((const float4*)ap)[i];
            #pragma unroll
            for (int issue = 0; issue < 4; ++issue) {
                int n = issue * 32 + sn;
                int csw = sc ^ ((n & 7) << 4);
                async_copy16((const char*)(Wb + (size_t)(bn + n) * H_ + (kt + 1) * 64) + csw,
                             (char*)Bl[1 - p] + issue * 4096 + wid * 1024);
            }
            asm volatile("s_waitcnt vmcnt(12) lgkmcnt(0)\ns_barrier" ::: "memory");
        } else {
            asm volatile("s_waitcnt vmcnt(0) lgkmcnt(0)\ns_barrier" ::: "memory");
        }
        // step4: MFMA
        {
            const char* pa = (const char*)Al[p];
            const char* pb = (const char*)Bl[p];
            #pragma unroll
            for (int ks = 0; ks < 2; ++ks) {
                bf16x8 afr[4], bfr[4];
                #pragma unroll
                for (int mi = 0; mi < 4; ++mi) {
                    int r  = wm * 64 + mi * 16 + (lane & 15);
                    int cb = (ks * 64 + (lane >> 4) * 16) ^ ((r & 7) << 4);
                    afr[mi] = *(const bf16x8*)(pa + r * 128 + cb);
                }
                #pragma unroll
                for (int ni = 0; ni < 4; ++ni) {
                    int r  = wn * 64 + ni * 16 + (lane & 15);
                    int cb = (ks * 64 + (lane >> 4) * 16) ^ ((r & 7) << 4);
                    bfr[ni] = *(const bf16x8*)(pb + r * 128 + cb);
                }
                #pragma unroll
                for (int mi = 0; mi < 4; ++mi)
                    #pragma unroll
                    for (int ni = 0; ni < 4; ++ni)
                        acc[mi][ni] = __builtin_amdgcn_mfma_f32_16x16x32_bf16(
                            afr[mi], bfr[ni], acc[mi][ni], 0, 0, 0);
            }
        }
        // step5
        asm volatile("s_barrier" ::: "memory");
    }

    const int gm0 = bm + wm * 64;
    const int gn0 = bn + wn * 64 + (lane & 15);

    if (EPI == 0) {
        const int b = bm >> 13;
        const int h = (bn >> 6) + wn;
        float ksv[4];
        #pragma unroll
        for (int ni = 0; ni < 4; ++ni)
            ksv[ni] = aux[((b * 16 + h) << 6) + ni * 16 + (lane & 15)];
        #pragma unroll
        for (int mi = 0; mi < 4; ++mi) {
            #pragma unroll
            for (int j = 0; j < 4; ++j) {
                float pv[4], s = 0.0f;
                #pragma unroll
                for (int ni = 0; ni < 4; ++ni) {
                    pv[ni] = phi_f(acc[mi][ni][j]);
                    s += pv[ni] * ksv[ni];
                }
                s += __shfl_xor(s, 1);
                s += __shfl_xor(s, 2);
                s += __shfl_xor(s, 4);
                s += __shfl_xor(s, 8);
                float z = 1.0f / (s + 1e-6f);
                int gm = gm0 + mi * 16 + (lane >> 4) * 4 + j;
                __bf16* op = Out + (size_t)gm * H_ + gn0;
                #pragma unroll
                for (int ni = 0; ni < 4; ++ni)
                    op[ni * 16] = (__bf16)(pv[ni] * z);
            }
        }
    } else {
        #pragma unroll
        for (int mi = 0; mi < 4; ++mi) {
            #pragma unroll
            for (int j = 0; j < 4; ++j) {
                int gm = gm0 + mi * 16 + (lane >> 4) * 4 + j;
                float mv = mask[gm];
                __bf16* op = Out + (size_t)gm * H_ + gn0;
                #pragma unroll
                for (int ni = 0; ni < 4; ++ni) {
                    float v = acc[mi][ni][j];
                    if (EPI == 1) v = phi_f(v) * mv;
                    else          v = v * mv;
                    op[ni * 16] = (__bf16)v;
                }
            }
        }
    }
}

// ---------------------------------------------------------------------------
// Final GEMM (bf16 A = Q', bf16 W = per-batch U): out fp32.  (round-8 body)
// ---------------------------------------------------------------------------
__global__ __launch_bounds__(256, 2)
void gemm_fin(const __bf16* __restrict__ A, const __bf16* __restrict__ Wb,
              float* __restrict__ Out)
{
    const int orig = blockIdx.x;
    const int wgid = (orig & 7) * 256 + (orig >> 3);
    const int bm = (wgid >> 3) * 128;
    const int bn = (wgid & 7) * 128;
    const int tid  = threadIdx.x;
    const int lane = tid & 63;
    const int wid  = tid >> 6;
    const int wm = wid >> 1, wn = wid & 1;

    const __bf16* Wp = Wb + ((size_t)(bm >> 13) << 20);   // per-batch U

    __shared__ __bf16 Al[128 * 64];
    __shared__ __bf16 Bl[128 * 64];

    f32x4 acc[4][4];
    #pragma unroll
    for (int i = 0; i < 4; ++i)
        #pragma unroll
        for (int j = 0; j < 4; ++j) acc[i][j] = (f32x4)0.0f;

    const int sn = wid * 8 + (lane >> 3);
    const int sc = (lane & 7) * 16;

    for (int k0 = 0; k0 < H_; k0 += 64) {
        #pragma unroll
        for (int issue = 0; issue < 4; ++issue) {
            int n = issue * 32 + sn;
            int csw = sc ^ ((n & 7) << 4);
            async_copy16((const char*)(A  + (size_t)(bm + n) * H_ + k0) + csw,
                         (char*)Al + issue * 4096 + wid * 1024);
            async_copy16((const char*)(Wp + (size_t)(bn + n) * H_ + k0) + csw,
                         (char*)Bl + issue * 4096 + wid * 1024);
        }
        __syncthreads();
        #pragma unroll
        for (int ks = 0; ks < 2; ++ks) {
            bf16x8 afr[4], bfr[4];
            #pragma unroll
            for (int mi = 0; mi < 4; ++mi) {
                int r  = wm * 64 + mi * 16 + (lane & 15);
                int cb = (ks * 64 + (lane >> 4) * 16) ^ ((r & 7) << 4);
                afr[mi] = *(const bf16x8*)((const char*)Al + r * 128 + cb);
            }
            #pragma unroll
            for (int ni = 0; ni < 4; ++ni) {
                int r  = wn * 64 + ni * 16 + (lane & 15);
                int cb = (ks * 64 + (lane >> 4) * 16) ^ ((r & 7) << 4);
                bfr[ni] = *(const bf16x8*)((const char*)Bl + r * 128 + cb);
            }
            #pragma unroll
            for (int mi = 0; mi < 4; ++mi)
                #pragma unroll
                for (int ni = 0; ni < 4; ++ni)
                    acc[mi][ni] = __builtin_amdgcn_mfma_f32_16x16x32_bf16(
                        afr[mi], bfr[ni], acc[mi][ni], 0, 0, 0);
        }
        __syncthreads();
    }
    const int gm0 = bm + wm * 64;
    const int gn0 = bn + wn * 64 + (lane & 15);
    #pragma unroll
    for (int mi = 0; mi < 4; ++mi)
        #pragma unroll
        for (int j = 0; j < 4; ++j) {
            int gm = gm0 + mi * 16 + (lane >> 4) * 4 + j;
            float* op = Out + (size_t)gm * H_ + gn0;
            #pragma unroll
            for (int ni = 0; ni < 4; ++ni)
                op[ni * 16] = acc[mi][ni][j];
        }
}

// ---------------------------------------------------------------------------
// KV partials via MFMA (unchanged, passing)
// ---------------------------------------------------------------------------
__global__ __launch_bounds__(256, 2)
void kv_kernel(const __bf16* __restrict__ Kb, const __bf16* __restrict__ Vb,
               float* __restrict__ KVp, float* __restrict__ Ksp)
{
    const int chunk = blockIdx.x;
    const int bh = blockIdx.y;
    const int b = bh >> 4, h = bh & 15;
    const int tid = threadIdx.x, lane = tid & 63, wid = tid >> 6;

    __shared__ char KtRaw[64 * 144];
    __shared__ char VtRaw[64 * 144];
    __shared__ float ksbuf[32][64];

    const int st  = tid >> 3;
    const int dkg = tid & 7;
    const int dk0 = dkg * 8;
    const int swzT = (dkg & 7) << 4;

    f32x4 acc[4];
    #pragma unroll
    for (int i = 0; i < 4; ++i) acc[i] = (f32x4)0.0f;
    float ksacc[8];
    #pragma unroll
    for (int i = 0; i < 8; ++i) ksacc[i] = 0.0f;

    const size_t gbase = ((size_t)b * T_ + (size_t)chunk * 1024) * H_
                         + h * 64 + dk0;

    bf16x8 ka, kc, va, vc;
    {
        const __bf16* p  = Kb + gbase;
        const __bf16* pv = Vb + gbase;
        ka = *(const bf16x8*)(p  + (size_t)st * H_);
        kc = *(const bf16x8*)(p  + (size_t)(st + 32) * H_);
        va = *(const bf16x8*)(pv + (size_t)st * H_);
        vc = *(const bf16x8*)(pv + (size_t)(st + 32) * H_);
    }

    for (int tile = 0; tile < 16; ++tile) {
        __syncthreads();
        #pragma unroll
        for (int j = 0; j < 8; ++j) {
            int rowb = (dk0 + j) * 144;
            *(__bf16*)(KtRaw + ((rowb + 2*st)        ^ swzT)) = ka[j];
            *(__bf16*)(KtRaw + ((rowb + 2*(st + 32)) ^ swzT)) = kc[j];
            *(__bf16*)(VtRaw + ((rowb + 2*st)        ^ swzT)) = va[j];
            *(__bf16*)(VtRaw + ((rowb + 2*(st + 32)) ^ swzT)) = vc[j];
            ksacc[j] += (float)ka[j] + (float)kc[j];
        }
        if (tile < 15) {
            const __bf16* p  = Kb + gbase + (size_t)(tile + 1) * 64 * H_;
            const __bf16* pv = Vb + gbase + (size_t)(tile + 1) * 64 * H_;
            ka = *(const bf16x8*)(p  + (size_t)st * H_);
            kc = *(const bf16x8*)(p  + (size_t)(st + 32) * H_);
            va = *(const bf16x8*)(pv + (size_t)st * H_);
            vc = *(const bf16x8*)(pv + (size_t)(st + 32) * H_);
        }
        __syncthreads();
        #pragma unroll
        for (int ks = 0; ks < 2; ++ks) {
            int r = wid * 16 + (lane & 15);
            int cb = (r * 144 + (ks * 64 + (lane >> 4) * 16)) ^ (((r >> 3) & 7) << 4);
            bf16x8 af = *(const bf16x8*)(KtRaw + cb);
            #pragma unroll
            for (int ni = 0; ni < 4; ++ni) {
                int rv = ni * 16 + (lane & 15);
                int cv = (rv * 144 + (ks * 64 + (lane >> 4) * 16)) ^ (((rv >> 3) & 7) << 4);
                bf16x8 bf = *(const bf16x8*)(VtRaw + cv);
                acc[ni] = __builtin_amdgcn_mfma_f32_16x16x32_bf16(af, bf, acc[ni], 0, 0, 0);
            }
        }
    }

    float* kvp = KVp + ((size_t)chunk * 64 + bh) * 4096;
    #pragma unroll
    for (int ni = 0; ni < 4; ++ni)
        #pragma unroll
        for (int jj = 0; jj < 4; ++jj) {
            int dk = wid * 16 + (lane >> 4) * 4 + jj;
            int dv = ni * 16 + (lane & 15);
            kvp[dk * 64 + dv] = acc[ni][jj];
        }

    #pragma unroll
    for (int j = 0; j < 8; ++j)
        ksbuf[st][dk0 + j] = ksacc[j];
    __syncthreads();
    if (tid < 64) {
        float s = 0.0f;
        #pragma unroll 8
        for (int st2 = 0; st2 < 32; ++st2) s += ksbuf[st2][tid];
        Ksp[((size_t)chunk * 64 + bh) * 64 + tid] = s;
    }
}

// sum 8 chunk-partials -> KVb bf16 [bh][dk][dv] + Ks fp32 [bh][dk]
__global__ void kvsum(const float* __restrict__ KVp, const float* __restrict__ Ksp,
                      __bf16* __restrict__ KVb, float* __restrict__ Ks) {
    int bh = blockIdx.x, tid = threadIdx.x;
    __bf16* d = KVb + (size_t)bh * 4096;
    for (int i = tid; i < 4096; i += 256) {
        float s = 0.0f;
        #pragma unroll
        for (int c = 0; c < 8; ++c)
            s += KVp[((size_t)c * 64 + bh) * 4096 + i];
        d[i] = (__bf16)s;
    }
    if (tid < 64) {
        float s = 0.0f;
        #pragma unroll
        for (int c = 0; c < 8; ++c)
            s += Ksp[((size_t)c * 64 + bh) * 64 + tid];
        Ks[bh * 64 + tid] = s;
    }
}

// ---------------------------------------------------------------------------
// Ut[b][m][h*64+dk] = sum_dv Wob[m][h*64+dv] * KVb[b*16+h][dk][dv]
// ---------------------------------------------------------------------------
__global__ __launch_bounds__(256)
void ugemm(const __bf16* __restrict__ Wob, const __bf16* __restrict__ KVb,
           __bf16* __restrict__ Ut)
{
    const int mp = blockIdx.x, bhp = blockIdx.y;
    const int b = bhp >> 3, hp = bhp & 7;
    const int tid = threadIdx.x, lane = tid & 63, w = tid >> 6;
    const int wm = w >> 1, wn = w & 1;
    const int h = hp * 2 + wn;
    const int bm = mp * 128;
    const int lane15 = lane & 15;

    __shared__ __bf16 As[128][136];
    __shared__ __bf16 Bs[2][64][72];

    {
        int r = tid >> 1, c0 = (tid & 1) * 64;
        const __bf16* src = Wob + (size_t)(bm + r) * H_ + hp * 128 + c0;
        #pragma unroll
        for (int j = 0; j < 8; ++j)
            *(bf16x8*)&As[r][c0 + j*8] = *(const bf16x8*)(src + j*8);
    }
    {
        int hh = tid >> 7, idx = tid & 127, r = idx >> 1, c0 = (idx & 1) * 32;
        const __bf16* src = KVb + ((size_t)(b * 16 + hp * 2 + hh) * 64 + r) * 64 + c0;
        #pragma unroll
        for (int j = 0; j < 4; ++j)
            *(bf16x8*)&Bs[hh][r][c0 + j*8] = *(const bf16x8*)(src + j*8);
    }
    __syncthreads();

    f32x4 acc[4][4];
    #pragma unroll
    for (int i = 0; i < 4; ++i)
        #pragma unroll
        for (int j = 0; j < 4; ++j) acc[i][j] = (f32x4)0.0f;

    #pragma unroll
    for (int ks = 0; ks < 2; ++ks) {
        bf16x8 afr[4], bfr[4];
        #pragma unroll
        for (int mi = 0; mi < 4; ++mi)
            afr[mi] = *(const bf16x8*)&As[wm*64 + mi*16 + lane15]
                                         [wn*64 + ks*32 + (lane>>4)*8];
        #pragma unroll
        for (int ni = 0; ni < 4; ++ni)
            bfr[ni] = *(const bf16x8*)&Bs[wn][ni*16 + lane15]
                                         [ks*32 + (lane>>4)*8];
        #pragma unroll
        for (int mi = 0; mi < 4; ++mi)
            #pragma unroll
            for (int ni = 0; ni < 4; ++ni)
                acc[mi][ni] = __builtin_amdgcn_mfma_f32_16x16x32_bf16(
                    afr[mi], bfr[ni], acc[mi][ni], 0, 0, 0);
    }

    __bf16* up = Ut + ((size_t)b << 20);
    #pragma unroll
    for (int mi = 0; mi < 4; ++mi)
        #pragma unroll
        for (int j = 0; j < 4; ++j) {
            int m2 = bm + wm * 64 + mi * 16 + (lane >> 4) * 4 + j;
            #pragma unroll
            for (int ni = 0; ni < 4; ++ni) {
                int dk = ni * 16 + lane15;
                up[(size_t)m2 * H_ + h * 64 + dk] = (__bf16)acc[mi][ni][j];
            }
        }
}

// ---------------------------------------------------------------------------
extern "C" void kernel_launch(void* const* d_in, const int* in_sizes, int n_in,
                              void* d_out, int out_size, void* d_ws, size_t ws_size,
                              hipStream_t stream) {
    (void)in_sizes; (void)n_in; (void)out_size; (void)ws_size;
    const float* q    = (const float*)d_in[0];
    const float* k    = (const float*)d_in[1];
    const float* v    = (const float*)d_in[2];
    const float* mask = (const float*)d_in[3];
    const float* Wq   = (const float*)d_in[4];
    const float* Wk   = (const float*)d_in[5];
    const float* Wv   = (const float*)d_in[6];
    const float* Wo   = (const float*)d_in[7];
    float* out = (float*)d_out;

    char* ws = (char*)d_ws;
    const size_t WELEM = (size_t)H_ * H_;
    const size_t PELEM = (size_t)BT_ * H_;
    __bf16* Wqb = (__bf16*)ws;
    __bf16* Wkb = Wqb + WELEM;
    __bf16* Wvb = Wkb + WELEM;
    __bf16* Wob = Wvb + WELEM;
    __bf16* Kb  = Wob + WELEM;
    __bf16* Vb  = Kb + PELEM;
    __bf16* Qb  = Vb + PELEM;
    float*  KVp = (float*)(Qb + PELEM);        // 8 MiB partials; reused as Ut
    float*  Ksp = KVp + (size_t)8 * 64 * 4096;
    float*  Ksf = Ksp + (size_t)8 * 64 * 64;
    __bf16* KVb = (__bf16*)(Ksf + (size_t)64 * 64);
    __bf16* Ut  = (__bf16*)KVp;                // aliases dead KVp
    // ws use ~209 MB

    wconv4<<<dim3(1024, 4), 256, 0, stream>>>(Wq, Wk, Wv, Wo, Wqb, Wkb, Wvb, Wob);

    gemm_fused<1><<<2048, 256, 0, stream>>>(k, Wkb, mask, nullptr, Kb);
    gemm_fused<2><<<2048, 256, 0, stream>>>(v, Wvb, mask, nullptr, Vb);

    kv_kernel<<<dim3(T_/1024, B_*NH_), 256, 0, stream>>>(Kb, Vb, KVp, Ksp);
    kvsum<<<B_*NH_, 256, 0, stream>>>(KVp, Ksp, KVb, Ksf);
    ugemm<<<dim3(8, 32), 256, 0, stream>>>(Wob, KVb, Ut);

    gemm_fused<0><<<2048, 256, 0, stream>>>(q, Wqb, mask, Ksf, Qb);
    gemm_fin<<<2048, 256, 0, stream>>>(Qb, Ut, out);
}

// Round 14
// 468.858 us; speedup vs baseline: 1.6799x; 1.6799x over previous
//
#include <hip/hip_runtime.h>
#include <hip/hip_bf16.h>
#include <stdint.h>

#define B_  4
#define T_  8192
#define H_  1024
#define NH_ 16
#define D_  64
#define BT_ (B_*T_)

typedef __attribute__((ext_vector_type(8))) __bf16 bf16x8;
typedef __attribute__((ext_vector_type(4))) __bf16 bf16x4;
typedef __attribute__((ext_vector_type(4))) float  f32x4;

template<int N> struct IC { static constexpr int v = N; };

__device__ __forceinline__ float phi_f(float x) {
    return x > 0.0f ? x + 1.0f : __expf(x);
}

__device__ __forceinline__ void async_copy16(const void* g, void* l) {
    __builtin_amdgcn_global_load_lds(
        (const __attribute__((address_space(1))) uint32_t*)g,
        (__attribute__((address_space(3))) uint32_t*)l, 16, 0, 0);
}

// ---------------------------------------------------------------------------
// fp32 -> bf16 conversion, 8 elems/thread
// ---------------------------------------------------------------------------
__global__ void conv_bf16(const float* __restrict__ src, __bf16* __restrict__ dst) {
    size_t i = ((size_t)blockIdx.x * 256 + threadIdx.x) * 8;
    float4 a = *(const float4*)(src + i);
    float4 b = *(const float4*)(src + i + 4);
    bf16x8 o;
    o[0]=(__bf16)a.x; o[1]=(__bf16)a.y; o[2]=(__bf16)a.z; o[3]=(__bf16)a.w;
    o[4]=(__bf16)b.x; o[5]=(__bf16)b.y; o[6]=(__bf16)b.z; o[7]=(__bf16)b.w;
    *(bf16x8*)(dst + i) = o;
}

__global__ void wconv4(const float* __restrict__ s0, const float* __restrict__ s1,
                       const float* __restrict__ s2, const float* __restrict__ s3,
                       __bf16* __restrict__ d0, __bf16* __restrict__ d1,
                       __bf16* __restrict__ d2, __bf16* __restrict__ d3) {
    const float* s; __bf16* d;
    switch (blockIdx.y) {
        case 0: s = s0; d = d0; break;
        case 1: s = s1; d = d1; break;
        case 2: s = s2; d = d2; break;
        default: s = s3; d = d3; break;
    }
    int i = (blockIdx.x * 256 + threadIdx.x) * 4;
    float4 v = *(const float4*)(s + i);
    bf16x4 o;
    o[0] = (__bf16)v.x; o[1] = (__bf16)v.y; o[2] = (__bf16)v.z; o[3] = (__bf16)v.w;
    *(bf16x4*)(d + i) = o;
}

// ---------------------------------------------------------------------------
// 128x128 GEMM (round-8, proven 904 TF): Out = epi(A @ W^T), both bf16 via
// global_load_lds.  EPI: 0 = Q' = z*phi (aux=Ksum), 1 = phi*mask, 2 = mask
// ---------------------------------------------------------------------------
template<int EPI>
__global__ __launch_bounds__(256, 2)
void gemm_bt(const __bf16* __restrict__ A, const __bf16* __restrict__ Wb,
             const float* __restrict__ mask, const float* __restrict__ aux,
             __bf16* __restrict__ Out)
{
    const int orig = blockIdx.x;
    const int wgid = (orig & 7) * 256 + (orig >> 3);
    const int bm = (wgid >> 3) * 128;
    const int bn = (wgid & 7) * 128;
    const int tid  = threadIdx.x;
    const int lane = tid & 63;
    const int wid  = tid >> 6;
    const int wm = wid >> 1, wn = wid & 1;

    __shared__ __bf16 Al[128 * 64];
    __shared__ __bf16 Bl[128 * 64];

    f32x4 acc[4][4];
    #pragma unroll
    for (int i = 0; i < 4; ++i)
        #pragma unroll
        for (int j = 0; j < 4; ++j) acc[i][j] = (f32x4)0.0f;

    const int sn = wid * 8 + (lane >> 3);
    const int sc = (lane & 7) * 16;

    for (int k0 = 0; k0 < H_; k0 += 64) {
        #pragma unroll
        for (int issue = 0; issue < 4; ++issue) {
            int n = issue * 32 + sn;
            int csw = sc ^ ((n & 7) << 4);
            async_copy16((const char*)(A  + (size_t)(bm + n) * H_ + k0) + csw,
                         (char*)Al + issue * 4096 + wid * 1024);
            async_copy16((const char*)(Wb + (size_t)(bn + n) * H_ + k0) + csw,
                         (char*)Bl + issue * 4096 + wid * 1024);
        }
        __syncthreads();
        #pragma unroll
        for (int ks = 0; ks < 2; ++ks) {
            bf16x8 afr[4], bfr[4];
            #pragma unroll
            for (int mi = 0; mi < 4; ++mi) {
                int r  = wm * 64 + mi * 16 + (lane & 15);
                int cb = (ks * 64 + (lane >> 4) * 16) ^ ((r & 7) << 4);
                afr[mi] = *(const bf16x8*)((const char*)Al + r * 128 + cb);
            }
            #pragma unroll
            for (int ni = 0; ni < 4; ++ni) {
                int r  = wn * 64 + ni * 16 + (lane & 15);
                int cb = (ks * 64 + (lane >> 4) * 16) ^ ((r & 7) << 4);
                bfr[ni] = *(const bf16x8*)((const char*)Bl + r * 128 + cb);
            }
            #pragma unroll
            for (int mi = 0; mi < 4; ++mi)
                #pragma unroll
                for (int ni = 0; ni < 4; ++ni)
                    acc[mi][ni] = __builtin_amdgcn_mfma_f32_16x16x32_bf16(
                        afr[mi], bfr[ni], acc[mi][ni], 0, 0, 0);
        }
        __syncthreads();
    }
    const int gm0 = bm + wm * 64;
    const int gn0 = bn + wn * 64 + (lane & 15);

    if (EPI == 0) {
        const int b = bm >> 13;
        const int h = (bn >> 6) + wn;
        float ksv[4];
        #pragma unroll
        for (int ni = 0; ni < 4; ++ni)
            ksv[ni] = aux[((b * 16 + h) << 6) + ni * 16 + (lane & 15)];
        #pragma unroll
        for (int mi = 0; mi < 4; ++mi) {
            #pragma unroll
            for (int j = 0; j < 4; ++j) {
                float pv[4], s = 0.0f;
                #pragma unroll
                for (int ni = 0; ni < 4; ++ni) {
                    pv[ni] = phi_f(acc[mi][ni][j]);
                    s += pv[ni] * ksv[ni];
                }
                s += __shfl_xor(s, 1);
                s += __shfl_xor(s, 2);
                s += __shfl_xor(s, 4);
                s += __shfl_xor(s, 8);
                float z = 1.0f / (s + 1e-6f);
                int gm = gm0 + mi * 16 + (lane >> 4) * 4 + j;
                __bf16* op = Out + (size_t)gm * H_ + gn0;
                #pragma unroll
                for (int ni = 0; ni < 4; ++ni)
                    op[ni * 16] = (__bf16)(pv[ni] * z);
            }
        }
    } else {
        #pragma unroll
        for (int mi = 0; mi < 4; ++mi) {
            #pragma unroll
            for (int j = 0; j < 4; ++j) {
                int gm = gm0 + mi * 16 + (lane >> 4) * 4 + j;
                float mv = mask[gm];
                __bf16* op = Out + (size_t)gm * H_ + gn0;
                #pragma unroll
                for (int ni = 0; ni < 4; ++ni) {
                    float v = acc[mi][ni][j];
                    if (EPI == 1) v = phi_f(v) * mv;
                    else          v = v * mv;
                    op[ni * 16] = (__bf16)v;
                }
            }
        }
    }
}

// ---------------------------------------------------------------------------
// 256x256 8-phase counted-vmcnt GEMM (final projection): out = Q' @ U^T, fp32.
// 512 thr = 8 waves (2M x 4N), per-wave 128x64.  BK=64, K-split halves.
// LDS: 2 buf x {Ah0,Ah1,Bh0,Bh1} halves, each [seg4][row256]x16B (seg-major:
// linear global_load_lds dest + per-lane permuted SOURCE; frag reads are
// 256B-contiguous per 16-lane group -> conflict-free).
// Per K-tile 4 phases (2 barriers each):
//   p0: ds_read 12 ks0 frags; stage Bh1(kt+1)->buf^1; bar; 16 MFMA m0-3; bar
//   p1: stage Ah0(kt+2)->buf; bar; 16 MFMA m4-7 ks0; bar
//   p2: ds_read 12 ks1 frags; stage Bh0(kt+2); bar; 16 MFMA m0-3 ks1; bar
//   p3: stage Ah1(kt+2); s_waitcnt vmcnt(6); bar; 16 MFMA m4-7 ks1; bar
// Ledger: wait at kt p3 retires through Bh1(kt+1) (worst case 10 outstanding,
// keep 6) -> all of kt+1 published by p3's barrier.  Prologue stages 7 halves
// then vmcnt(6).  Tails: kt=14 vmcnt(0), kt=15 no wait.  No asm lgkm (compiler
// handles ds_read->MFMA register deps).
// ---------------------------------------------------------------------------
__global__ __launch_bounds__(512, 2)
void gemm256_fin(const __bf16* __restrict__ A, const __bf16* __restrict__ Wb,
                 float* __restrict__ Out)
{
    __shared__ __align__(16) char lds[131072];

    const int orig = blockIdx.x;
    const int wg = (orig & 7) * 64 + (orig >> 3);   // 512 wgs, bijective
    const int bm = (wg >> 2) * 256;
    const int bn = (wg & 3) * 256;
    const int tid = threadIdx.x, lane = tid & 63, w = tid >> 6;
    const int wm = w >> 2, wn = w & 3;
    const int lane15 = lane & 15, q = lane >> 4;

    const __bf16* Wp = Wb + ((size_t)(bm >> 13) << 20);   // per-batch U

    // staging: thread covers row=tid&255, segs {tid>>8, tid>>8+2}
    const int srow = tid & 255;
    const char* gA0 = (const char*)(A  + (size_t)(bm + srow) * H_) + (tid >> 8) * 16;
    const char* gB0 = (const char*)(Wp + (size_t)(bn + srow) * H_) + (tid >> 8) * 16;
    const int d0 = w * 1024;   // HW adds lane*16

    auto ST = [&](int buf, int isB, int hk, int kt) {
        const int kb = kt * 128 + hk * 64;
        const char* s = isB ? gB0 : gA0;
        char* d = (char*)lds + buf * 65536 + isB * 32768 + hk * 16384 + d0;
        async_copy16(s + kb, d);
        async_copy16(s + kb + 32, d + 8192);
    };

    f32x4 acc[8][4];
    #pragma unroll
    for (int i = 0; i < 8; ++i)
        #pragma unroll
        for (int j = 0; j < 4; ++j) acc[i][j] = (f32x4)0.0f;

    const int arowoff = (wm * 128 + lane15) * 16;   // + mi*256
    const int browoff = (wn * 64  + lane15) * 16;   // + ni*256

    bf16x8 aF[8], bF[4];

    auto body = [&](auto dbc, int kt, int sn1, int sn2, int wmode) {
        constexpr int DB = decltype(dbc)::v;
        const char* base = (const char*)lds + DB * 65536 + q * 4096;
        // ---- p0: ks0 frag reads + stage Bh1(kt+1) ----
        #pragma unroll
        for (int mi = 0; mi < 8; ++mi)
            aF[mi] = *(const bf16x8*)(base + arowoff + mi * 256);
        #pragma unroll
        for (int ni = 0; ni < 4; ++ni)
            bF[ni] = *(const bf16x8*)(base + 32768 + browoff + ni * 256);
        if (sn1) ST(DB ^ 1, 1, 1, kt + 1);
        __builtin_amdgcn_s_barrier();
        __builtin_amdgcn_s_setprio(1);
        #pragma unroll
        for (int mi = 0; mi < 4; ++mi)
            #pragma unroll
            for (int ni = 0; ni < 4; ++ni)
                acc[mi][ni] = __builtin_amdgcn_mfma_f32_16x16x32_bf16(
                    aF[mi], bF[ni], acc[mi][ni], 0, 0, 0);
        __builtin_amdgcn_s_setprio(0);
        __builtin_amdgcn_s_barrier();
        // ---- p1: stage Ah0(kt+2); MFMA m4-7 ks0 ----
        if (sn2) ST(DB, 0, 0, kt + 2);
        __builtin_amdgcn_s_barrier();
        __builtin_amdgcn_s_setprio(1);
        #pragma unroll
        for (int mi = 4; mi < 8; ++mi)
            #pragma unroll
            for (int ni = 0; ni < 4; ++ni)
                acc[mi][ni] = __builtin_amdgcn_mfma_f32_16x16x32_bf16(
                    aF[mi], bF[ni], acc[mi][ni], 0, 0, 0);
        __builtin_amdgcn_s_setprio(0);
        __builtin_amdgcn_s_barrier();
        // ---- p2: ks1 frag reads + stage Bh0(kt+2); MFMA m0-3 ks1 ----
        #pragma unroll
        for (int mi = 0; mi < 8; ++mi)
            aF[mi] = *(const bf16x8*)(base + 16384 + arowoff + mi * 256);
        #pragma unroll
        for (int ni = 0; ni < 4; ++ni)
            bF[ni] = *(const bf16x8*)(base + 49152 + browoff + ni * 256);
        if (sn2) ST(DB, 1, 0, kt + 2);
        __builtin_amdgcn_s_barrier();
        __builtin_amdgcn_s_setprio(1);
        #pragma unroll
        for (int mi = 0; mi < 4; ++mi)
            #pragma unroll
            for (int ni = 0; ni < 4; ++ni)
                acc[mi][ni] = __builtin_amdgcn_mfma_f32_16x16x32_bf16(
                    aF[mi], bF[ni], acc[mi][ni], 0, 0, 0);
        __builtin_amdgcn_s_setprio(0);
        __builtin_amdgcn_s_barrier();
        // ---- p3: stage Ah1(kt+2); counted wait; MFMA m4-7 ks1 ----
        if (sn2) ST(DB, 0, 1, kt + 2);
        if (wmode == 0)      asm volatile("s_waitcnt vmcnt(6)" ::: "memory");
        else if (wmode == 1) asm volatile("s_waitcnt vmcnt(0)" ::: "memory");
        __builtin_amdgcn_s_barrier();
        __builtin_amdgcn_s_setprio(1);
        #pragma unroll
        for (int mi = 4; mi < 8; ++mi)
            #pragma unroll
            for (int ni = 0; ni < 4; ++ni)
                acc[mi][ni] = __builtin_amdgcn_mfma_f32_16x16x32_bf16(
                    aF[mi], bF[ni], acc[mi][ni], 0, 0, 0);
        __builtin_amdgcn_s_setprio(0);
        __builtin_amdgcn_s_barrier();
    };

    // prologue: buf0 all 4 halves of kt0, buf1 Ah0/Bh0/Ah1 of kt1 (14 loads)
    ST(0, 0, 0, 0); ST(0, 1, 0, 0); ST(0, 0, 1, 0); ST(0, 1, 1, 0);
    ST(1, 0, 0, 1); ST(1, 1, 0, 1); ST(1, 0, 1, 1);
    asm volatile("s_waitcnt vmcnt(6)" ::: "memory");
    __builtin_amdgcn_s_barrier();

    #pragma unroll 1
    for (int kt2 = 0; kt2 < 12; kt2 += 2) {
        body(IC<0>{}, kt2,     1, 1, 0);
        body(IC<1>{}, kt2 + 1, 1, 1, 0);
    }
    body(IC<0>{}, 12, 1, 1, 0);
    body(IC<1>{}, 13, 1, 1, 0);
    body(IC<0>{}, 14, 1, 0, 1);
    body(IC<1>{}, 15, 0, 0, 2);

    // epilogue: C row = (lane>>4)*4 + j, col = lane&15
    const int gm0 = bm + wm * 128;
    const int gn0 = bn + wn * 64 + lane15;
    #pragma unroll
    for (int mi = 0; mi < 8; ++mi)
        #pragma unroll
        for (int j = 0; j < 4; ++j) {
            int gm = gm0 + mi * 16 + (lane >> 4) * 4 + j;
            float* op = Out + (size_t)gm * H_ + gn0;
            #pragma unroll
            for (int ni = 0; ni < 4; ++ni)
                op[ni * 16] = acc[mi][ni][j];
        }
}

// ---------------------------------------------------------------------------
// KV partials via MFMA (unchanged, passing)
// ---------------------------------------------------------------------------
__global__ __launch_bounds__(256, 2)
void kv_kernel(const __bf16* __restrict__ Kb, const __bf16* __restrict__ Vb,
               float* __restrict__ KVp, float* __restrict__ Ksp)
{
    const int chunk = blockIdx.x;
    const int bh = blockIdx.y;
    const int b = bh >> 4, h = bh & 15;
    const int tid = threadIdx.x, lane = tid & 63, wid = tid >> 6;

    __shared__ char KtRaw[64 * 144];
    __shared__ char VtRaw[64 * 144];
    __shared__ float ksbuf[32][64];

    const int st  = tid >> 3;
    const int dkg = tid & 7;
    const int dk0 = dkg * 8;
    const int swzT = (dkg & 7) << 4;

    f32x4 acc[4];
    #pragma unroll
    for (int i = 0; i < 4; ++i) acc[i] = (f32x4)0.0f;
    float ksacc[8];
    #pragma unroll
    for (int i = 0; i < 8; ++i) ksacc[i] = 0.0f;

    const size_t gbase = ((size_t)b * T_ + (size_t)chunk * 1024) * H_
                         + h * 64 + dk0;

    bf16x8 ka, kc, va, vc;
    {
        const __bf16* p  = Kb + gbase;
        const __bf16* pv = Vb + gbase;
        ka = *(const bf16x8*)(p  + (size_t)st * H_);
        kc = *(const bf16x8*)(p  + (size_t)(st + 32) * H_);
        va = *(const bf16x8*)(pv + (size_t)st * H_);
        vc = *(const bf16x8*)(pv + (size_t)(st + 32) * H_);
    }

    for (int tile = 0; tile < 16; ++tile) {
        __syncthreads();
        #pragma unroll
        for (int j = 0; j < 8; ++j) {
            int rowb = (dk0 + j) * 144;
            *(__bf16*)(KtRaw + ((rowb + 2*st)        ^ swzT)) = ka[j];
            *(__bf16*)(KtRaw + ((rowb + 2*(st + 32)) ^ swzT)) = kc[j];
            *(__bf16*)(VtRaw + ((rowb + 2*st)        ^ swzT)) = va[j];
            *(__bf16*)(VtRaw + ((rowb + 2*(st + 32)) ^ swzT)) = vc[j];
            ksacc[j] += (float)ka[j] + (float)kc[j];
        }
        if (tile < 15) {
            const __bf16* p  = Kb + gbase + (size_t)(tile + 1) * 64 * H_;
            const __bf16* pv = Vb + gbase + (size_t)(tile + 1) * 64 * H_;
            ka = *(const bf16x8*)(p  + (size_t)st * H_);
            kc = *(const bf16x8*)(p  + (size_t)(st + 32) * H_);
            va = *(const bf16x8*)(pv + (size_t)st * H_);
            vc = *(const bf16x8*)(pv + (size_t)(st + 32) * H_);
        }
        __syncthreads();
        #pragma unroll
        for (int ks = 0; ks < 2; ++ks) {
            int r = wid * 16 + (lane & 15);
            int cb = (r * 144 + (ks * 64 + (lane >> 4) * 16)) ^ (((r >> 3) & 7) << 4);
            bf16x8 af = *(const bf16x8*)(KtRaw + cb);
            #pragma unroll
            for (int ni = 0; ni < 4; ++ni) {
                int rv = ni * 16 + (lane & 15);
                int cv = (rv * 144 + (ks * 64 + (lane >> 4) * 16)) ^ (((rv >> 3) & 7) << 4);
                bf16x8 bf = *(const bf16x8*)(VtRaw + cv);
                acc[ni] = __builtin_amdgcn_mfma_f32_16x16x32_bf16(af, bf, acc[ni], 0, 0, 0);
            }
        }
    }

    float* kvp = KVp + ((size_t)chunk * 64 + bh) * 4096;
    #pragma unroll
    for (int ni = 0; ni < 4; ++ni)
        #pragma unroll
        for (int jj = 0; jj < 4; ++jj) {
            int dk = wid * 16 + (lane >> 4) * 4 + jj;
            int dv = ni * 16 + (lane & 15);
            kvp[dk * 64 + dv] = acc[ni][jj];
        }

    #pragma unroll
    for (int j = 0; j < 8; ++j)
        ksbuf[st][dk0 + j] = ksacc[j];
    __syncthreads();
    if (tid < 64) {
        float s = 0.0f;
        #pragma unroll 8
        for (int st2 = 0; st2 < 32; ++st2) s += ksbuf[st2][tid];
        Ksp[((size_t)chunk * 64 + bh) * 64 + tid] = s;
    }
}

// sum 8 chunk-partials -> KVb bf16 [bh][dk][dv] + Ks fp32 [bh][dk]
__global__ void kvsum(const float* __restrict__ KVp, const float* __restrict__ Ksp,
                      __bf16* __restrict__ KVb, float* __restrict__ Ks) {
    int bh = blockIdx.x, tid = threadIdx.x;
    __bf16* d = KVb + (size_t)bh * 4096;
    for (int i = tid; i < 4096; i += 256) {
        float s = 0.0f;
        #pragma unroll
        for (int c = 0; c < 8; ++c)
            s += KVp[((size_t)c * 64 + bh) * 4096 + i];
        d[i] = (__bf16)s;
    }
    if (tid < 64) {
        float s = 0.0f;
        #pragma unroll
        for (int c = 0; c < 8; ++c)
            s += Ksp[((size_t)c * 64 + bh) * 64 + tid];
        Ks[bh * 64 + tid] = s;
    }
}

// ---------------------------------------------------------------------------
// Ut[b][m][h*64+dk] = sum_dv Wob[m][h*64+dv] * KVb[b*16+h][dk][dv]
// ---------------------------------------------------------------------------
__global__ __launch_bounds__(256)
void ugemm(const __bf16* __restrict__ Wob, const __bf16* __restrict__ KVb,
           __bf16* __restrict__ Ut)
{
    const int mp = blockIdx.x, bhp = blockIdx.y;
    const int b = bhp >> 3, hp = bhp & 7;
    const int tid = threadIdx.x, lane = tid & 63, w = tid >> 6;
    const int wm = w >> 1, wn = w & 1;
    const int h = hp * 2 + wn;
    const int bm = mp * 128;
    const int lane15 = lane & 15;

    __shared__ __bf16 As[128][136];
    __shared__ __bf16 Bs[2][64][72];

    {
        int r = tid >> 1, c0 = (tid & 1) * 64;
        const __bf16* src = Wob + (size_t)(bm + r) * H_ + hp * 128 + c0;
        #pragma unroll
        for (int j = 0; j < 8; ++j)
            *(bf16x8*)&As[r][c0 + j*8] = *(const bf16x8*)(src + j*8);
    }
    {
        int hh = tid >> 7, idx = tid & 127, r = idx >> 1, c0 = (idx & 1) * 32;
        const __bf16* src = KVb + ((size_t)(b * 16 + hp * 2 + hh) * 64 + r) * 64 + c0;
        #pragma unroll
        for (int j = 0; j < 4; ++j)
            *(bf16x8*)&Bs[hh][r][c0 + j*8] = *(const bf16x8*)(src + j*8);
    }
    __syncthreads();

    f32x4 acc[4][4];
    #pragma unroll
    for (int i = 0; i < 4; ++i)
        #pragma unroll
        for (int j = 0; j < 4; ++j) acc[i][j] = (f32x4)0.0f;

    #pragma unroll
    for (int ks = 0; ks < 2; ++ks) {
        bf16x8 afr[4], bfr[4];
        #pragma unroll
        for (int mi = 0; mi < 4; ++mi)
            afr[mi] = *(const bf16x8*)&As[wm*64 + mi*16 + lane15]
                                         [wn*64 + ks*32 + (lane>>4)*8];
        #pragma unroll
        for (int ni = 0; ni < 4; ++ni)
            bfr[ni] = *(const bf16x8*)&Bs[wn][ni*16 + lane15]
                                         [ks*32 + (lane>>4)*8];
        #pragma unroll
        for (int mi = 0; mi < 4; ++mi)
            #pragma unroll
            for (int ni = 0; ni < 4; ++ni)
                acc[mi][ni] = __builtin_amdgcn_mfma_f32_16x16x32_bf16(
                    afr[mi], bfr[ni], acc[mi][ni], 0, 0, 0);
    }

    __bf16* up = Ut + ((size_t)b << 20);
    #pragma unroll
    for (int mi = 0; mi < 4; ++mi)
        #pragma unroll
        for (int j = 0; j < 4; ++j) {
            int m2 = bm + wm * 64 + mi * 16 + (lane >> 4) * 4 + j;
            #pragma unroll
            for (int ni = 0; ni < 4; ++ni) {
                int dk = ni * 16 + lane15;
                up[(size_t)m2 * H_ + h * 64 + dk] = (__bf16)acc[mi][ni][j];
            }
        }
}

// ---------------------------------------------------------------------------
extern "C" void kernel_launch(void* const* d_in, const int* in_sizes, int n_in,
                              void* d_out, int out_size, void* d_ws, size_t ws_size,
                              hipStream_t stream) {
    (void)in_sizes; (void)n_in; (void)out_size; (void)ws_size;
    const float* q    = (const float*)d_in[0];
    const float* k    = (const float*)d_in[1];
    const float* v    = (const float*)d_in[2];
    const float* mask = (const float*)d_in[3];
    const float* Wq   = (const float*)d_in[4];
    const float* Wk   = (const float*)d_in[5];
    const float* Wv   = (const float*)d_in[6];
    const float* Wo   = (const float*)d_in[7];
    float* out = (float*)d_out;

    char* ws = (char*)d_ws;
    const size_t WELEM = (size_t)H_ * H_;
    const size_t PELEM = (size_t)BT_ * H_;
    __bf16* Wqb = (__bf16*)ws;
    __bf16* Wkb = Wqb + WELEM;
    __bf16* Wvb = Wkb + WELEM;
    __bf16* Wob = Wvb + WELEM;
    __bf16* Qb  = Wob + WELEM;                 // Q' buffer
    __bf16* Kb  = Qb + PELEM;
    __bf16* Vb  = Kb + PELEM;
    __bf16* tmp = Vb + PELEM;                  // conv scratch
    float*  KVp = (float*)(tmp + PELEM);       // 8 MiB partials; reused as Ut
    float*  Ksp = KVp + (size_t)8 * 64 * 4096;
    float*  Ksf = Ksp + (size_t)8 * 64 * 64;
    __bf16* KVb = (__bf16*)(Ksf + (size_t)64 * 64);
    __bf16* Ut  = (__bf16*)KVp;                // aliases dead KVp

    wconv4<<<dim3(1024, 4), 256, 0, stream>>>(Wq, Wk, Wv, Wo, Wqb, Wkb, Wvb, Wob);

    const int cgrid = (int)(PELEM / (256 * 8));   // 16384
    conv_bf16<<<cgrid, 256, 0, stream>>>(k, tmp);
    gemm_bt<1><<<2048, 256, 0, stream>>>(tmp, Wkb, mask, nullptr, Kb);
    conv_bf16<<<cgrid, 256, 0, stream>>>(v, tmp);
    gemm_bt<2><<<2048, 256, 0, stream>>>(tmp, Wvb, mask, nullptr, Vb);

    kv_kernel<<<dim3(T_/1024, B_*NH_), 256, 0, stream>>>(Kb, Vb, KVp, Ksp);
    kvsum<<<B_*NH_, 256, 0, stream>>>(KVp, Ksp, KVb, Ksf);
    ugemm<<<dim3(8, 32), 256, 0, stream>>>(Wob, KVb, Ut);

    conv_bf16<<<cgrid, 256, 0, stream>>>(q, tmp);
    gemm_bt<0><<<2048, 256, 0, stream>>>(tmp, Wqb, mask, Ksf, Qb);

    gemm256_fin<<<512, 512, 0, stream>>>(Qb, Ut, out);
}

// Round 15
// 425.393 us; speedup vs baseline: 1.8515x; 1.1022x over previous
//
#include <hip/hip_runtime.h>
#include <hip/hip_bf16.h>
#include <stdint.h>

#define B_  4
#define T_  8192
#define H_  1024
#define NH_ 16
#define D_  64
#define BT_ (B_*T_)

typedef __attribute__((ext_vector_type(8))) __bf16 bf16x8;
typedef __attribute__((ext_vector_type(4))) __bf16 bf16x4;
typedef __attribute__((ext_vector_type(4))) float  f32x4;

__device__ __forceinline__ float phi_f(float x) {
    return x > 0.0f ? x + 1.0f : __expf(x);
}

__device__ __forceinline__ void async_copy16(const void* g, void* l) {
    __builtin_amdgcn_global_load_lds(
        (const __attribute__((address_space(1))) uint32_t*)g,
        (__attribute__((address_space(3))) uint32_t*)l, 16, 0, 0);
}

// ---------------------------------------------------------------------------
// fp32 -> bf16 conversion, 8 elems/thread (BW-roofline pass, ~30 us)
// ---------------------------------------------------------------------------
__global__ void conv_bf16(const float* __restrict__ src, __bf16* __restrict__ dst) {
    size_t i = ((size_t)blockIdx.x * 256 + threadIdx.x) * 8;
    float4 a = *(const float4*)(src + i);
    float4 b = *(const float4*)(src + i + 4);
    bf16x8 o;
    o[0]=(__bf16)a.x; o[1]=(__bf16)a.y; o[2]=(__bf16)a.z; o[3]=(__bf16)a.w;
    o[4]=(__bf16)b.x; o[5]=(__bf16)b.y; o[6]=(__bf16)b.z; o[7]=(__bf16)b.w;
    *(bf16x8*)(dst + i) = o;
}

__global__ void wconv4(const float* __restrict__ s0, const float* __restrict__ s1,
                       const float* __restrict__ s2, const float* __restrict__ s3,
                       __bf16* __restrict__ d0, __bf16* __restrict__ d1,
                       __bf16* __restrict__ d2, __bf16* __restrict__ d3) {
    const float* s; __bf16* d;
    switch (blockIdx.y) {
        case 0: s = s0; d = d0; break;
        case 1: s = s1; d = d1; break;
        case 2: s = s2; d = d2; break;
        default: s = s3; d = d3; break;
    }
    int i = (blockIdx.x * 256 + threadIdx.x) * 4;
    float4 v = *(const float4*)(s + i);
    bf16x4 o;
    o[0] = (__bf16)v.x; o[1] = (__bf16)v.y; o[2] = (__bf16)v.z; o[3] = (__bf16)v.w;
    *(bf16x4*)(d + i) = o;
}

// ---------------------------------------------------------------------------
// 128x128 GEMM (m97-structure, 904 TF = plain-HIP structural ceiling):
// Out = epi(A @ W^T), both operands bf16 via global_load_lds (pre-swizzled
// source -> XOR-swizzled conflict-free ds_read_b128).  XCD-bijective 1D
// block swizzle keeps each XCD's A-panels L2-resident.
// EPI: 0 = Q' = z*phi -> bf16 (aux = Ksum; z = 1/(phi(Q).Ksum + 1e-6))
//      1 = phi*mask -> bf16 (K),  2 = mask -> bf16 (V)
//      3 = none -> fp32 (final; W is per-batch U: Wb + (bm>>13)<<20)
// ---------------------------------------------------------------------------
template<int EPI>
__global__ __launch_bounds__(256, 2)
void gemm_bt(const __bf16* __restrict__ A, const __bf16* __restrict__ Wb,
             const float* __restrict__ mask, const float* __restrict__ aux,
             void* __restrict__ OutV)
{
    const int orig = blockIdx.x;
    const int wgid = (orig & 7) * 256 + (orig >> 3);   // nwg=2048, %8==0: bijective
    const int bm = (wgid >> 3) * 128;
    const int bn = (wgid & 7) * 128;
    const int tid  = threadIdx.x;
    const int lane = tid & 63;
    const int wid  = tid >> 6;
    const int wm = wid >> 1, wn = wid & 1;

    const __bf16* Wp = Wb;
    if (EPI == 3) Wp = Wb + ((size_t)(bm >> 13) << 20);   // per-batch U

    __shared__ __bf16 Al[128 * 64];
    __shared__ __bf16 Bl[128 * 64];

    f32x4 acc[4][4];
    #pragma unroll
    for (int i = 0; i < 4; ++i)
        #pragma unroll
        for (int j = 0; j < 4; ++j) acc[i][j] = (f32x4)0.0f;

    const int sn = wid * 8 + (lane >> 3);
    const int sc = (lane & 7) * 16;

    for (int k0 = 0; k0 < H_; k0 += 64) {
        #pragma unroll
        for (int issue = 0; issue < 4; ++issue) {
            int n = issue * 32 + sn;
            int csw = sc ^ ((n & 7) << 4);
            async_copy16((const char*)(A  + (size_t)(bm + n) * H_ + k0) + csw,
                         (char*)Al + issue * 4096 + wid * 1024);
            async_copy16((const char*)(Wp + (size_t)(bn + n) * H_ + k0) + csw,
                         (char*)Bl + issue * 4096 + wid * 1024);
        }
        __syncthreads();
        #pragma unroll
        for (int ks = 0; ks < 2; ++ks) {
            bf16x8 afr[4], bfr[4];
            #pragma unroll
            for (int mi = 0; mi < 4; ++mi) {
                int r  = wm * 64 + mi * 16 + (lane & 15);
                int cb = (ks * 64 + (lane >> 4) * 16) ^ ((r & 7) << 4);
                afr[mi] = *(const bf16x8*)((const char*)Al + r * 128 + cb);
            }
            #pragma unroll
            for (int ni = 0; ni < 4; ++ni) {
                int r  = wn * 64 + ni * 16 + (lane & 15);
                int cb = (ks * 64 + (lane >> 4) * 16) ^ ((r & 7) << 4);
                bfr[ni] = *(const bf16x8*)((const char*)Bl + r * 128 + cb);
            }
            #pragma unroll
            for (int mi = 0; mi < 4; ++mi)
                #pragma unroll
                for (int ni = 0; ni < 4; ++ni)
                    acc[mi][ni] = __builtin_amdgcn_mfma_f32_16x16x32_bf16(
                        afr[mi], bfr[ni], acc[mi][ni], 0, 0, 0);
        }
        __syncthreads();
    }
    // epilogue: C row = (lane>>4)*4 + j, col = lane&15
    const int gm0 = bm + wm * 64;
    const int gn0 = bn + wn * 64 + (lane & 15);

    if (EPI == 0) {
        // z-scaled phi(Q): wave covers one full head (64 cols); 16-lane
        // butterfly gives each row its denominator (fp32, better than the
        // old bf16-Q path).
        const int b = bm >> 13;
        const int h = (bn >> 6) + wn;
        float ksv[4];
        #pragma unroll
        for (int ni = 0; ni < 4; ++ni)
            ksv[ni] = aux[((b * 16 + h) << 6) + ni * 16 + (lane & 15)];
        #pragma unroll
        for (int mi = 0; mi < 4; ++mi) {
            #pragma unroll
            for (int j = 0; j < 4; ++j) {
                float pv[4], s = 0.0f;
                #pragma unroll
                for (int ni = 0; ni < 4; ++ni) {
                    pv[ni] = phi_f(acc[mi][ni][j]);
                    s += pv[ni] * ksv[ni];
                }
                s += __shfl_xor(s, 1);
                s += __shfl_xor(s, 2);
                s += __shfl_xor(s, 4);
                s += __shfl_xor(s, 8);
                float z = 1.0f / (s + 1e-6f);
                int gm = gm0 + mi * 16 + (lane >> 4) * 4 + j;
                __bf16* op = (__bf16*)OutV + (size_t)gm * H_ + gn0;
                #pragma unroll
                for (int ni = 0; ni < 4; ++ni)
                    op[ni * 16] = (__bf16)(pv[ni] * z);
            }
        }
    } else {
        #pragma unroll
        for (int mi = 0; mi < 4; ++mi) {
            #pragma unroll
            for (int j = 0; j < 4; ++j) {
                int gm = gm0 + mi * 16 + (lane >> 4) * 4 + j;
                if (EPI == 3) {
                    float* op = (float*)OutV + (size_t)gm * H_ + gn0;
                    #pragma unroll
                    for (int ni = 0; ni < 4; ++ni)
                        op[ni * 16] = acc[mi][ni][j];
                } else {
                    float mv = mask[gm];
                    __bf16* op = (__bf16*)OutV + (size_t)gm * H_ + gn0;
                    #pragma unroll
                    for (int ni = 0; ni < 4; ++ni) {
                        float v = acc[mi][ni][j];
                        if (EPI == 1) v = phi_f(v) * mv;
                        else          v = v * mv;
                        op[ni * 16] = (__bf16)v;
                    }
                }
            }
        }
    }
}

// ---------------------------------------------------------------------------
// KV partials via MFMA: KVp[chunk][bh][dk][dv], Ksp[chunk][bh][dk].
// Transposed LDS staging (scalar b16 writes, 144B stride + XOR swizzle),
// non-atomic partial stores, deterministic Ksum tree.
// ---------------------------------------------------------------------------
__global__ __launch_bounds__(256, 2)
void kv_kernel(const __bf16* __restrict__ Kb, const __bf16* __restrict__ Vb,
               float* __restrict__ KVp, float* __restrict__ Ksp)
{
    const int chunk = blockIdx.x;
    const int bh = blockIdx.y;
    const int b = bh >> 4, h = bh & 15;
    const int tid = threadIdx.x, lane = tid & 63, wid = tid >> 6;

    __shared__ char KtRaw[64 * 144];
    __shared__ char VtRaw[64 * 144];
    __shared__ float ksbuf[32][64];

    const int st  = tid >> 3;
    const int dkg = tid & 7;
    const int dk0 = dkg * 8;
    const int swzT = (dkg & 7) << 4;

    f32x4 acc[4];
    #pragma unroll
    for (int i = 0; i < 4; ++i) acc[i] = (f32x4)0.0f;
    float ksacc[8];
    #pragma unroll
    for (int i = 0; i < 8; ++i) ksacc[i] = 0.0f;

    const size_t gbase = ((size_t)b * T_ + (size_t)chunk * 1024) * H_
                         + h * 64 + dk0;

    bf16x8 ka, kc, va, vc;
    {
        const __bf16* p  = Kb + gbase;
        const __bf16* pv = Vb + gbase;
        ka = *(const bf16x8*)(p  + (size_t)st * H_);
        kc = *(const bf16x8*)(p  + (size_t)(st + 32) * H_);
        va = *(const bf16x8*)(pv + (size_t)st * H_);
        vc = *(const bf16x8*)(pv + (size_t)(st + 32) * H_);
    }

    for (int tile = 0; tile < 16; ++tile) {
        __syncthreads();
        #pragma unroll
        for (int j = 0; j < 8; ++j) {
            int rowb = (dk0 + j) * 144;
            *(__bf16*)(KtRaw + ((rowb + 2*st)        ^ swzT)) = ka[j];
            *(__bf16*)(KtRaw + ((rowb + 2*(st + 32)) ^ swzT)) = kc[j];
            *(__bf16*)(VtRaw + ((rowb + 2*st)        ^ swzT)) = va[j];
            *(__bf16*)(VtRaw + ((rowb + 2*(st + 32)) ^ swzT)) = vc[j];
            ksacc[j] += (float)ka[j] + (float)kc[j];
        }
        if (tile < 15) {
            const __bf16* p  = Kb + gbase + (size_t)(tile + 1) * 64 * H_;
            const __bf16* pv = Vb + gbase + (size_t)(tile + 1) * 64 * H_;
            ka = *(const bf16x8*)(p  + (size_t)st * H_);
            kc = *(const bf16x8*)(p  + (size_t)(st + 32) * H_);
            va = *(const bf16x8*)(pv + (size_t)st * H_);
            vc = *(const bf16x8*)(pv + (size_t)(st + 32) * H_);
        }
        __syncthreads();
        #pragma unroll
        for (int ks = 0; ks < 2; ++ks) {
            int r = wid * 16 + (lane & 15);
            int cb = (r * 144 + (ks * 64 + (lane >> 4) * 16)) ^ (((r >> 3) & 7) << 4);
            bf16x8 af = *(const bf16x8*)(KtRaw + cb);
            #pragma unroll
            for (int ni = 0; ni < 4; ++ni) {
                int rv = ni * 16 + (lane & 15);
                int cv = (rv * 144 + (ks * 64 + (lane >> 4) * 16)) ^ (((rv >> 3) & 7) << 4);
                bf16x8 bf = *(const bf16x8*)(VtRaw + cv);
                acc[ni] = __builtin_amdgcn_mfma_f32_16x16x32_bf16(af, bf, acc[ni], 0, 0, 0);
            }
        }
    }

    float* kvp = KVp + ((size_t)chunk * 64 + bh) * 4096;
    #pragma unroll
    for (int ni = 0; ni < 4; ++ni)
        #pragma unroll
        for (int jj = 0; jj < 4; ++jj) {
            int dk = wid * 16 + (lane >> 4) * 4 + jj;
            int dv = ni * 16 + (lane & 15);
            kvp[dk * 64 + dv] = acc[ni][jj];
        }

    #pragma unroll
    for (int j = 0; j < 8; ++j)
        ksbuf[st][dk0 + j] = ksacc[j];
    __syncthreads();
    if (tid < 64) {
        float s = 0.0f;
        #pragma unroll 8
        for (int st2 = 0; st2 < 32; ++st2) s += ksbuf[st2][tid];
        Ksp[((size_t)chunk * 64 + bh) * 64 + tid] = s;
    }
}

// sum 8 chunk-partials -> KVb bf16 [bh][dk][dv] + Ks fp32 [bh][dk]
__global__ void kvsum(const float* __restrict__ KVp, const float* __restrict__ Ksp,
                      __bf16* __restrict__ KVb, float* __restrict__ Ks) {
    int bh = blockIdx.x, tid = threadIdx.x;
    __bf16* d = KVb + (size_t)bh * 4096;
    for (int i = tid; i < 4096; i += 256) {
        float s = 0.0f;
        #pragma unroll
        for (int c = 0; c < 8; ++c)
            s += KVp[((size_t)c * 64 + bh) * 4096 + i];
        d[i] = (__bf16)s;
    }
    if (tid < 64) {
        float s = 0.0f;
        #pragma unroll
        for (int c = 0; c < 8; ++c)
            s += Ksp[((size_t)c * 64 + bh) * 64 + tid];
        Ks[bh * 64 + tid] = s;
    }
}

// ---------------------------------------------------------------------------
// Ut[b][m][h*64+dk] = sum_dv Wob[m][h*64+dv] * KVb[b*16+h][dk][dv]
// (associativity fusion: out = Q' @ U^T deletes the attn pass entirely)
// ---------------------------------------------------------------------------
__global__ __launch_bounds__(256)
void ugemm(const __bf16* __restrict__ Wob, const __bf16* __restrict__ KVb,
           __bf16* __restrict__ Ut)
{
    const int mp = blockIdx.x, bhp = blockIdx.y;
    const int b = bhp >> 3, hp = bhp & 7;
    const int tid = threadIdx.x, lane = tid & 63, w = tid >> 6;
    const int wm = w >> 1, wn = w & 1;
    const int h = hp * 2 + wn;
    const int bm = mp * 128;
    const int lane15 = lane & 15;

    __shared__ __bf16 As[128][136];
    __shared__ __bf16 Bs[2][64][72];

    {
        int r = tid >> 1, c0 = (tid & 1) * 64;
        const __bf16* src = Wob + (size_t)(bm + r) * H_ + hp * 128 + c0;
        #pragma unroll
        for (int j = 0; j < 8; ++j)
            *(bf16x8*)&As[r][c0 + j*8] = *(const bf16x8*)(src + j*8);
    }
    {
        int hh = tid >> 7, idx = tid & 127, r = idx >> 1, c0 = (idx & 1) * 32;
        const __bf16* src = KVb + ((size_t)(b * 16 + hp * 2 + hh) * 64 + r) * 64 + c0;
        #pragma unroll
        for (int j = 0; j < 4; ++j)
            *(bf16x8*)&Bs[hh][r][c0 + j*8] = *(const bf16x8*)(src + j*8);
    }
    __syncthreads();

    f32x4 acc[4][4];
    #pragma unroll
    for (int i = 0; i < 4; ++i)
        #pragma unroll
        for (int j = 0; j < 4; ++j) acc[i][j] = (f32x4)0.0f;

    #pragma unroll
    for (int ks = 0; ks < 2; ++ks) {
        bf16x8 afr[4], bfr[4];
        #pragma unroll
        for (int mi = 0; mi < 4; ++mi)
            afr[mi] = *(const bf16x8*)&As[wm*64 + mi*16 + lane15]
                                         [wn*64 + ks*32 + (lane>>4)*8];
        #pragma unroll
        for (int ni = 0; ni < 4; ++ni)
            bfr[ni] = *(const bf16x8*)&Bs[wn][ni*16 + lane15]
                                         [ks*32 + (lane>>4)*8];
        #pragma unroll
        for (int mi = 0; mi < 4; ++mi)
            #pragma unroll
            for (int ni = 0; ni < 4; ++ni)
                acc[mi][ni] = __builtin_amdgcn_mfma_f32_16x16x32_bf16(
                    afr[mi], bfr[ni], acc[mi][ni], 0, 0, 0);
    }

    __bf16* up = Ut + ((size_t)b << 20);
    #pragma unroll
    for (int mi = 0; mi < 4; ++mi)
        #pragma unroll
        for (int j = 0; j < 4; ++j) {
            int m2 = bm + wm * 64 + mi * 16 + (lane >> 4) * 4 + j;
            #pragma unroll
            for (int ni = 0; ni < 4; ++ni) {
                int dk = ni * 16 + lane15;
                up[(size_t)m2 * H_ + h * 64 + dk] = (__bf16)acc[mi][ni][j];
            }
        }
}

// ---------------------------------------------------------------------------
extern "C" void kernel_launch(void* const* d_in, const int* in_sizes, int n_in,
                              void* d_out, int out_size, void* d_ws, size_t ws_size,
                              hipStream_t stream) {
    (void)in_sizes; (void)n_in; (void)out_size; (void)ws_size;
    const float* q    = (const float*)d_in[0];
    const float* k    = (const float*)d_in[1];
    const float* v    = (const float*)d_in[2];
    const float* mask = (const float*)d_in[3];
    const float* Wq   = (const float*)d_in[4];
    const float* Wk   = (const float*)d_in[5];
    const float* Wv   = (const float*)d_in[6];
    const float* Wo   = (const float*)d_in[7];
    float* out = (float*)d_out;

    char* ws = (char*)d_ws;
    const size_t WELEM = (size_t)H_ * H_;
    const size_t PELEM = (size_t)BT_ * H_;
    __bf16* Wqb = (__bf16*)ws;
    __bf16* Wkb = Wqb + WELEM;
    __bf16* Wvb = Wkb + WELEM;
    __bf16* Wob = Wvb + WELEM;
    __bf16* Qb  = Wob + WELEM;                 // Q' buffer
    __bf16* Kb  = Qb + PELEM;
    __bf16* Vb  = Kb + PELEM;
    __bf16* tmp = Vb + PELEM;                  // conv scratch
    float*  KVp = (float*)(tmp + PELEM);       // 8 MiB partials; reused as Ut
    float*  Ksp = KVp + (size_t)8 * 64 * 4096;
    float*  Ksf = Ksp + (size_t)8 * 64 * 64;
    __bf16* KVb = (__bf16*)(Ksf + (size_t)64 * 64);
    __bf16* Ut  = (__bf16*)KVp;                // aliases dead KVp (8 MiB)
    // total ws use ~273 MB

    wconv4<<<dim3(1024, 4), 256, 0, stream>>>(Wq, Wk, Wv, Wo, Wqb, Wkb, Wvb, Wob);

    const int cgrid = (int)(PELEM / (256 * 8));   // 16384
    conv_bf16<<<cgrid, 256, 0, stream>>>(k, tmp);
    gemm_bt<1><<<2048, 256, 0, stream>>>(tmp, Wkb, mask, nullptr, Kb);
    conv_bf16<<<cgrid, 256, 0, stream>>>(v, tmp);
    gemm_bt<2><<<2048, 256, 0, stream>>>(tmp, Wvb, mask, nullptr, Vb);

    kv_kernel<<<dim3(T_/1024, B_*NH_), 256, 0, stream>>>(Kb, Vb, KVp, Ksp);
    kvsum<<<B_*NH_, 256, 0, stream>>>(KVp, Ksp, KVb, Ksf);
    ugemm<<<dim3(8, 32), 256, 0, stream>>>(Wob, KVb, Ut);

    conv_bf16<<<cgrid, 256, 0, stream>>>(q, tmp);
    gemm_bt<0><<<2048, 256, 0, stream>>>(tmp, Wqb, mask, Ksf, Qb);
    gemm_bt<3><<<2048, 256, 0, stream>>>(Qb, Ut, mask, nullptr, out);
}